// Round 1
// baseline (1068.261 us; speedup 1.0000x reference)
//
#include <hip/hip_runtime.h>
#include <math.h>

// Problem constants (from reference setup_inputs)
#define NN    5000      // nodes
#define NE    80000     // edges
#define NB    32        // batch
#define DIN   16        // input feat
#define CH    64        // conv channels
#define KPOOL 30
#define FTOT  208       // 16 + 3*64
#define FLATW 6241      // KPOOL*FTOT + 1
#define NH    128       // MLP hidden

// ---------------- setup kernels ----------------

__global__ void k_init(float* deg, int* counts, float* stats, float* hm) {
    int i = blockIdx.x * 256 + threadIdx.x;
    if (i < NN) { deg[i] = 1.0f; counts[i] = 0; }   // deg starts at self-loop value 1
    if (i < 256) stats[i] = 0.0f;
    if (i < 4096) hm[i] = 0.0f;
}

__global__ void k_edges(const float* __restrict__ attr, const int* __restrict__ erow,
                        float* deg, int* counts) {
    int e = blockIdx.x * 256 + threadIdx.x;
    if (e < NE) {
        int r = erow[e];
        atomicAdd(&deg[r], attr[e]);
        atomicAdd(&counts[r], 1);
    }
}

__global__ void k_dinv(const float* __restrict__ deg, float* dinv) {
    int i = blockIdx.x * 256 + threadIdx.x;
    if (i < NN) dinv[i] = 1.0f / sqrtf(deg[i]);    // deg >= 1 always
}

__global__ void k_scan(const int* __restrict__ counts, int* rowptr, int* cursor) {
    __shared__ int buf[1024];
    __shared__ int carry;
    int t = threadIdx.x;
    if (t == 0) carry = 0;
    __syncthreads();
    for (int base = 0; base < NN; base += 1024) {
        int i = base + t;
        int v = (i < NN) ? counts[i] : 0;
        buf[t] = v;
        __syncthreads();
        for (int off = 1; off < 1024; off <<= 1) {
            int add = (t >= off) ? buf[t - off] : 0;
            __syncthreads();
            buf[t] += add;
            __syncthreads();
        }
        if (i < NN) {
            int inc = buf[t] + carry;   // inclusive prefix
            rowptr[i + 1] = inc;
            cursor[i] = inc - v;        // exclusive prefix
        }
        __syncthreads();
        if (t == 1023) carry += buf[1023];
        __syncthreads();
    }
    if (t == 0) rowptr[0] = 0;
}

__global__ void k_scatter(const int* __restrict__ erow, const int* __restrict__ ecol,
                          const float* __restrict__ attr, const float* __restrict__ dinv,
                          int* cursor, int* csr_col, float* csr_nv) {
    int e = blockIdx.x * 256 + threadIdx.x;
    if (e < NE) {
        int r = erow[e], c = ecol[e];
        int pos = atomicAdd(&cursor[r], 1);
        csr_col[pos] = c;
        csr_nv[pos] = dinv[r] * attr[e] * dinv[c];
    }
}

// ---------------- SPMM (aggregate) ----------------
// out[b,r,c] = selfnv[r]*act(in[b,r,c]) + sum_edges nv*act(in[b,col,c])
// ACT: 0 = identity, 1 = BN(scale/shift in st) + ReLU
template<int C, int ACT>
__global__ void k_spmm(const float* __restrict__ in, const float* __restrict__ st,
                       const int* __restrict__ rowptr, const int* __restrict__ csr_col,
                       const float* __restrict__ csr_nv, const float* __restrict__ dinv,
                       float* __restrict__ out) {
    constexpr int RPB = 256 / C;
    int tid = threadIdx.x;
    int c = tid % C;
    int r = blockIdx.x * RPB + tid / C;
    int b = blockIdx.y;
    if (r >= NN) return;
    float sv = 0.f, tv = 0.f;
    if (ACT == 1) { sv = st[c]; tv = st[C + c]; }
    const float* __restrict__ base = in + (size_t)b * NN * C;
    float d = dinv[r];
    float v0 = base[(size_t)r * C + c];
    if (ACT == 1) v0 = fmaxf(fmaf(v0, sv, tv), 0.f);
    float acc = d * d * v0;   // self-loop: nv = dinv[r]^2
    int p0 = rowptr[r], p1 = rowptr[r + 1];
    for (int p = p0; p < p1; ++p) {
        int col = csr_col[p];
        float w = csr_nv[p];
        float v = base[(size_t)col * C + c];
        if (ACT == 1) v = fmaxf(fmaf(v, sv, tv), 0.f);
        acc = fmaf(w, v, acc);
    }
    out[((size_t)b * NN + r) * C + c] = acc;
}

// ---------------- node-wise GEMM: out[b,n,:] = in[b,n,:] @ W + bias ----------------
template<int CIN>
__global__ void k_gemm(const float* __restrict__ in, const float* __restrict__ W,
                       const float* __restrict__ bias, float* __restrict__ out) {
    __shared__ float Wl[CIN * 64];
    int tid = threadIdx.x;
    for (int i = tid; i < CIN * 64; i += 256) Wl[i] = W[i];
    __syncthreads();
    int j = tid & 63, sub = tid >> 6;
    int n = blockIdx.x * 4 + sub, b = blockIdx.y;
    if (n >= NN) return;
    const float4* row = (const float4*)(in + ((size_t)b * NN + n) * CIN);
    float acc = bias[j];
#pragma unroll
    for (int k4 = 0; k4 < CIN / 4; ++k4) {
        float4 rv = row[k4];
        acc = fmaf(rv.x, Wl[(k4 * 4 + 0) * 64 + j], acc);
        acc = fmaf(rv.y, Wl[(k4 * 4 + 1) * 64 + j], acc);
        acc = fmaf(rv.z, Wl[(k4 * 4 + 2) * 64 + j], acc);
        acc = fmaf(rv.w, Wl[(k4 * 4 + 3) * 64 + j], acc);
    }
    out[((size_t)b * NN + n) * 64 + j] = acc;
}

// ---------------- BatchNorm stats ----------------
__global__ void k_stats(const float* __restrict__ h, float* stats) {
    int tid = threadIdx.x;
    int c = tid & 63;
    float s = 0.f, q = 0.f;
    for (int row = blockIdx.x * 4 + (tid >> 6); row < NB * NN; row += gridDim.x * 4) {
        float v = h[(size_t)row * 64 + c];
        s += v;
        q = fmaf(v, v, q);
    }
    __shared__ float ls[256], lq[256];
    ls[tid] = s; lq[tid] = q;
    __syncthreads();
    if (tid < 64) {
        s = ls[tid] + ls[tid + 64] + ls[tid + 128] + ls[tid + 192];
        q = lq[tid] + lq[tid + 64] + lq[tid + 128] + lq[tid + 192];
        atomicAdd(&stats[tid], s);
        atomicAdd(&stats[64 + tid], q);
    }
}

__global__ void k_bnfin(const float* __restrict__ stats, const float* __restrict__ g,
                        const float* __restrict__ be, float* st) {
    int c = threadIdx.x;  // 64
    const float inv = 1.0f / (float)(NB * NN);
    float mu = stats[c] * inv;
    float var = stats[64 + c] * inv - mu * mu;
    float sc = g[c] / sqrtf(var + 1e-5f);
    st[c] = sc;
    st[64 + c] = fmaf(-mu, sc, be[c]);
}

// ---------------- global_sort_pool: top-30 stable argmax ----------------
__global__ void k_toppool(const float* __restrict__ h3, int* order) {
    __shared__ float v[NN];
    __shared__ float bestv[256];
    __shared__ int besti[256];
    int b = blockIdx.x, tid = threadIdx.x;
    for (int i = tid; i < NN; i += 256)
        v[i] = fmaxf(h3[((size_t)b * NN + i) * 64 + 63], 0.f);  // relu'd last channel
    __syncthreads();
    for (int k = 0; k < KPOOL; ++k) {
        float bv = -1.f; int bi = NN;
        for (int i = tid; i < NN; i += 256) {
            float x = v[i];
            if (x > bv || (x == bv && i < bi)) { bv = x; bi = i; }
        }
        bestv[tid] = bv; besti[tid] = bi;
        __syncthreads();
        for (int off = 128; off > 0; off >>= 1) {
            if (tid < off) {
                float ov = bestv[tid + off]; int oi = besti[tid + off];
                if (ov > bestv[tid] || (ov == bestv[tid] && oi < besti[tid])) {
                    bestv[tid] = ov; besti[tid] = oi;
                }
            }
            __syncthreads();
        }
        if (tid == 0) { order[b * KPOOL + k] = besti[0]; v[besti[0]] = -1.f; }
        __syncthreads();
    }
}

// ---------------- gather selected nodes into flat (B, 6241) ----------------
__global__ void k_gather(const float* __restrict__ x, const float* __restrict__ h1,
                         const float* __restrict__ h2, const float* __restrict__ h3,
                         const float* __restrict__ st, const float* __restrict__ age,
                         const int* __restrict__ order, float* __restrict__ flat) {
    int bk = blockIdx.x;
    int b = bk / KPOOL, k = bk % KPOOL;
    int n = order[bk];
    int f = threadIdx.x;
    float val = 0.f;
    if (f < DIN) {
        val = x[((size_t)b * NN + n) * DIN + f];
    } else if (f < DIN + CH) {
        int c = f - DIN;
        val = fmaxf(fmaf(h1[((size_t)b * NN + n) * CH + c], st[c], st[64 + c]), 0.f);
    } else if (f < DIN + 2 * CH) {
        int c = f - DIN - CH;
        val = fmaxf(fmaf(h2[((size_t)b * NN + n) * CH + c], st[128 + c], st[192 + c]), 0.f);
    } else if (f < FTOT) {
        int c = f - DIN - 2 * CH;
        val = fmaxf(h3[((size_t)b * NN + n) * CH + c], 0.f);
    }
    if (f < FTOT) flat[(size_t)b * FLATW + k * FTOT + f] = val;
    if (bk == 0 && f >= FTOT && f < FTOT + NB)
        flat[(size_t)(f - FTOT) * FLATW + (FLATW - 1)] = age[f - FTOT];
}

// ---------------- MLP head layer 1: hm += flat @ mW0 (k-split, atomics) ----------------
__global__ void k_head1(const float* __restrict__ flat, const float* __restrict__ mW0,
                        float* hm) {
    int tid = threadIdx.x;
    int j4 = (tid & 31) * 4;       // 32 groups * 4 = 128 cols
    int b0 = (tid >> 5) * 4;       // 8 groups * 4 = 32 rows
    int kbase = blockIdx.x * 64;
    float acc[4][4];
#pragma unroll
    for (int i = 0; i < 4; i++)
#pragma unroll
        for (int jj = 0; jj < 4; jj++) acc[i][jj] = 0.f;
    int kend = FLATW - kbase; if (kend > 64) kend = 64;
    for (int kk = 0; kk < kend; ++kk) {
        int k = kbase + kk;
        float4 w = *(const float4*)(mW0 + (size_t)k * NH + j4);
#pragma unroll
        for (int i = 0; i < 4; i++) {
            float fv = flat[(size_t)(b0 + i) * FLATW + k];
            acc[i][0] = fmaf(fv, w.x, acc[i][0]);
            acc[i][1] = fmaf(fv, w.y, acc[i][1]);
            acc[i][2] = fmaf(fv, w.z, acc[i][2]);
            acc[i][3] = fmaf(fv, w.w, acc[i][3]);
        }
    }
#pragma unroll
    for (int i = 0; i < 4; i++)
#pragma unroll
        for (int jj = 0; jj < 4; jj++)
            atomicAdd(&hm[(size_t)(b0 + i) * NH + j4 + jj], acc[i][jj]);
}

// ---------------- head layer 2 + log_softmax ----------------
__global__ void k_head2(const float* __restrict__ hm, const float* __restrict__ mb0,
                        const float* __restrict__ mW1, const float* __restrict__ mb1,
                        float* __restrict__ out) {
    __shared__ float vals[64];
    int tid = threadIdx.x;  // 64 = 32 b * 2 o
    int b = tid >> 1, o = tid & 1;
    float acc = mb1[o];
    for (int j = 0; j < NH; ++j) {
        float hv = fmaxf(hm[b * NH + j] + mb0[j], 0.f);
        acc = fmaf(hv, mW1[j * 2 + o], acc);
    }
    vals[tid] = acc;
    __syncthreads();
    float v0 = vals[b * 2], v1 = vals[b * 2 + 1];
    float m = fmaxf(v0, v1);
    float lse = m + logf(expf(v0 - m) + expf(v1 - m));
    out[tid] = acc - lse;
}

extern "C" void kernel_launch(void* const* d_in, const int* in_sizes, int n_in,
                              void* d_out, int out_size, void* d_ws, size_t ws_size,
                              hipStream_t stream) {
    const float* x    = (const float*)d_in[0];
    const float* age  = (const float*)d_in[1];
    const float* attr = (const float*)d_in[2];
    const float* W0   = (const float*)d_in[3];
    const float* b0   = (const float*)d_in[4];
    const float* W1   = (const float*)d_in[5];
    const float* b1   = (const float*)d_in[6];
    const float* W2   = (const float*)d_in[7];
    const float* b2   = (const float*)d_in[8];
    const float* g0   = (const float*)d_in[9];
    const float* be0  = (const float*)d_in[10];
    const float* g1   = (const float*)d_in[11];
    const float* be1  = (const float*)d_in[12];
    const float* mW0  = (const float*)d_in[13];
    const float* mb0  = (const float*)d_in[14];
    const float* mW1  = (const float*)d_in[15];
    const float* mb1  = (const float*)d_in[16];
    const int* erow   = (const int*)d_in[17];
    const int* ecol   = (const int*)d_in[18];
    float* out = (float*)d_out;

    // workspace layout (floats); all float4-aligned
    float* ws     = (float*)d_ws;
    float* deg    = ws;                                  // 5008
    float* dinv   = deg + 5008;                          // 5008
    int*   counts = (int*)(dinv + 5008);                 // 5008
    int*   rowptr = counts + 5008;                       // 5008
    int*   cursor = rowptr + 5008;                       // 5008
    int*   csr_col= cursor + 5008;                       // 80000
    float* csr_nv = (float*)(csr_col + 80000);           // 80000
    float* stats  = csr_nv + 80000;                      // 256
    float* st     = stats + 256;                         // 256 (s0,t0,s1,t1)
    int*   order  = (int*)(st + 256);                    // 960
    float* flat   = (float*)(order + 960);               // 32*6241
    float* hm     = flat + (size_t)NB * FLATW;           // 4096
    float* agg    = hm + 4096;                           // 32*5000*64
    float* h1     = agg + (size_t)NB * NN * CH;
    float* h2     = h1 + (size_t)NB * NN * CH;
    float* h3     = h2 + (size_t)NB * NN * CH;

    // graph build
    k_init<<<20, 256, 0, stream>>>(deg, counts, stats, hm);
    k_edges<<<(NE + 255) / 256, 256, 0, stream>>>(attr, erow, deg, counts);
    k_dinv<<<(NN + 255) / 256, 256, 0, stream>>>(deg, dinv);
    k_scan<<<1, 1024, 0, stream>>>(counts, rowptr, cursor);
    k_scatter<<<(NE + 255) / 256, 256, 0, stream>>>(erow, ecol, attr, dinv, cursor, csr_col, csr_nv);

    // layer 0: agg = spmm(x); h1raw = agg @ W0 + b0
    k_spmm<16, 0><<<dim3(313, NB), 256, 0, stream>>>(x, nullptr, rowptr, csr_col, csr_nv, dinv, agg);
    k_gemm<16><<<dim3(1250, NB), 256, 0, stream>>>(agg, W0, b0, h1);
    k_stats<<<512, 256, 0, stream>>>(h1, stats);
    k_bnfin<<<1, 64, 0, stream>>>(stats, g0, be0, st);

    // layer 1: agg = spmm(act0(h1raw)); h2raw = agg @ W1 + b1
    k_spmm<64, 1><<<dim3(1250, NB), 256, 0, stream>>>(h1, st, rowptr, csr_col, csr_nv, dinv, agg);
    k_gemm<64><<<dim3(1250, NB), 256, 0, stream>>>(agg, W1, b1, h2);
    k_stats<<<512, 256, 0, stream>>>(h2, stats + 128);
    k_bnfin<<<1, 64, 0, stream>>>(stats + 128, g1, be1, st + 128);

    // layer 2: agg = spmm(act1(h2raw)); h3raw = agg @ W2 + b2
    k_spmm<64, 1><<<dim3(1250, NB), 256, 0, stream>>>(h2, st + 128, rowptr, csr_col, csr_nv, dinv, agg);
    k_gemm<64><<<dim3(1250, NB), 256, 0, stream>>>(agg, W2, b2, h3);

    // sort-pool + gather + head
    k_toppool<<<NB, 256, 0, stream>>>(h3, order);
    k_gather<<<NB * KPOOL, 256, 0, stream>>>(x, h1, h2, h3, st, age, order, flat);
    k_head1<<<(FLATW + 63) / 64, 256, 0, stream>>>(flat, mW0, hm);
    k_head2<<<1, 64, 0, stream>>>(hm, mb0, mW1, mb1, out);
}

// Round 3
// 910.877 us; speedup vs baseline: 1.1728x; 1.1728x over previous
//
#include <hip/hip_runtime.h>
#include <math.h>

// Problem constants (from reference setup_inputs)
#define NN    5000      // nodes
#define NE    80000     // edges
#define NB    32        // batch
#define DIN   16        // input feat
#define CH    64        // conv channels
#define KPOOL 30
#define FTOT  208       // 16 + 3*64
#define FLATW 6241      // KPOOL*FTOT + 1
#define NH    128       // MLP hidden

// All intermediate feature tensors use NODE-MAJOR layout: (N, B, C).
// One edge gather then reads a contiguous 32*C*4 bytes row shared by all batches.

// ---------------- setup kernels ----------------

__global__ void k_init(float* deg, int* counts, float* stats, float* hm) {
    int i = blockIdx.x * 256 + threadIdx.x;
    if (i < NN) { deg[i] = 1.0f; counts[i] = 0; }   // deg starts at self-loop value 1
    if (i < 256) stats[i] = 0.0f;
    if (i < 4096) hm[i] = 0.0f;
}

__global__ void k_edges(const float* __restrict__ attr, const int* __restrict__ erow,
                        float* deg, int* counts) {
    int e = blockIdx.x * 256 + threadIdx.x;
    if (e < NE) {
        int r = erow[e];
        atomicAdd(&deg[r], attr[e]);
        atomicAdd(&counts[r], 1);
    }
}

__global__ void k_dinv(const float* __restrict__ deg, float* dinv) {
    int i = blockIdx.x * 256 + threadIdx.x;
    if (i < NN) dinv[i] = 1.0f / sqrtf(deg[i]);    // deg >= 1 always
}

__global__ void k_scan(const int* __restrict__ counts, int* rowptr, int* cursor) {
    __shared__ int buf[1024];
    __shared__ int carry;
    int t = threadIdx.x;
    if (t == 0) carry = 0;
    __syncthreads();
    for (int base = 0; base < NN; base += 1024) {
        int i = base + t;
        int v = (i < NN) ? counts[i] : 0;
        buf[t] = v;
        __syncthreads();
        for (int off = 1; off < 1024; off <<= 1) {
            int add = (t >= off) ? buf[t - off] : 0;
            __syncthreads();
            buf[t] += add;
            __syncthreads();
        }
        if (i < NN) {
            int inc = buf[t] + carry;   // inclusive prefix
            rowptr[i + 1] = inc;
            cursor[i] = inc - v;        // exclusive prefix
        }
        __syncthreads();
        if (t == 1023) carry += buf[1023];
        __syncthreads();
    }
    if (t == 0) rowptr[0] = 0;
}

__global__ void k_scatter(const int* __restrict__ erow, const int* __restrict__ ecol,
                          const float* __restrict__ attr, const float* __restrict__ dinv,
                          int* cursor, int* csr_col, float* csr_nv) {
    int e = blockIdx.x * 256 + threadIdx.x;
    if (e < NE) {
        int r = erow[e], c = ecol[e];
        int pos = atomicAdd(&cursor[r], 1);
        csr_col[pos] = c;
        csr_nv[pos] = dinv[r] * attr[e] * dinv[c];
    }
}

// transpose x (B,N,16) -> xt (N,B,16)
__global__ void k_transpose(const float* __restrict__ x, float* __restrict__ xt) {
    int idx = blockIdx.x * 256 + threadIdx.x;   // over B*N rows, b-major for coalesced reads
    if (idx >= NB * NN) return;
    int b = idx / NN, n = idx % NN;
    const float4* src = (const float4*)(x + (size_t)idx * DIN);
    float4* dst = (float4*)(xt + ((size_t)n * NB + b) * DIN);
    dst[0] = src[0]; dst[1] = src[1]; dst[2] = src[2]; dst[3] = src[3];
}

// ---------------- fused GCN layer ----------------
// One block per node r. Stage 1: agg[b][k] = sum over (self + edges) of
// nv * act(in[col][b][k]) where act = optional BN(scale/shift)+ReLU of the
// PREVIOUS layer's raw output. Stage 2: out[r][b][j] = agg[b][:] @ W + bias.
// STATS: accumulate per-channel sum/sumsq of out into stats[128] (for BN).
template<int CIN, int ACT, int STATS>
__global__ __launch_bounds__(256) void k_layer(
        const float* __restrict__ in, const float* __restrict__ st,
        const float* __restrict__ W, const float* __restrict__ bias,
        const int* __restrict__ rowptr, const int* __restrict__ csr_col,
        const float* __restrict__ csr_nv, const float* __restrict__ dinv,
        float* __restrict__ out, float* __restrict__ stats) {
    constexpr int BSUB = 256 / CIN;     // batches covered per pass (4 or 16)
    constexpr int NPASS = 32 / BSUB;    // 8 or 2
    __shared__ float Wl[CIN * 64];
    __shared__ float Al[32 * (CIN + 1)];   // padded leading dim (+1) -> no bank conflict
    __shared__ float SQ[STATS ? 2048 : 1]; // dedicated stats scratch (R2 bug: reused Al, too small for CIN=16)
    __shared__ int ecol[64];
    __shared__ float ew[64];
    int tid = threadIdx.x;
    int r = blockIdx.x;
    for (int i = tid; i < CIN * 64; i += 256) Wl[i] = W[i];

    int c = tid % CIN;
    int bs = tid / CIN;
    float sv = 1.f, tv = 0.f;
    if (ACT) { sv = st[c]; tv = st[CIN + c]; }
    float acc[NPASS];
    float d = dinv[r];
    float dd = d * d;   // self-loop weight
    {
        const float* __restrict__ rp = in + (size_t)r * NB * CIN;
#pragma unroll
        for (int i = 0; i < NPASS; ++i) {
            float v = rp[(i * BSUB + bs) * CIN + c];
            if (ACT) v = fmaxf(fmaf(v, sv, tv), 0.f);
            acc[i] = dd * v;
        }
    }
    int p0 = rowptr[r], p1 = rowptr[r + 1];
    for (int pb = p0; pb < p1; pb += 64) {
        int cnt = min(64, p1 - pb);
        __syncthreads();
        if (tid < cnt) { ecol[tid] = csr_col[pb + tid]; ew[tid] = csr_nv[pb + tid]; }
        __syncthreads();
        for (int e = 0; e < cnt; ++e) {
            const float* __restrict__ rp = in + (size_t)ecol[e] * NB * CIN;
            float w = ew[e];
#pragma unroll
            for (int i = 0; i < NPASS; ++i) {
                float v = rp[(i * BSUB + bs) * CIN + c];   // contiguous 256B per wave
                if (ACT) v = fmaxf(fmaf(v, sv, tv), 0.f);
                acc[i] = fmaf(w, v, acc[i]);
            }
        }
    }
#pragma unroll
    for (int i = 0; i < NPASS; ++i) Al[(i * BSUB + bs) * (CIN + 1) + c] = acc[i];
    __syncthreads();

    // Stage 2: GEMM. thread -> (j4 = 4 output channels, brow = batch row), 2 passes.
    int j4 = (tid & 15) * 4;
    int brow = tid >> 4;   // 16 batch rows per pass
    float4 bia = *(const float4*)(bias + j4);
    float4 o[2];
#pragma unroll
    for (int pass = 0; pass < 2; ++pass) {
        int b = pass * 16 + brow;
        float4 o_ = bia;
#pragma unroll
        for (int k = 0; k < CIN; ++k) {
            float a = Al[b * (CIN + 1) + k];
            float4 w4 = *(const float4*)(Wl + k * 64 + j4);
            o_.x = fmaf(a, w4.x, o_.x);
            o_.y = fmaf(a, w4.y, o_.y);
            o_.z = fmaf(a, w4.z, o_.z);
            o_.w = fmaf(a, w4.w, o_.w);
        }
        *(float4*)(out + ((size_t)r * NB + b) * 64 + j4) = o_;
        o[pass] = o_;
    }

    if (STATS) {
        float* S = SQ;            // [16][64]
        float* Q = SQ + 1024;     // [16][64]
        float4 s4, q4;
        s4.x = o[0].x + o[1].x;  q4.x = o[0].x * o[0].x + o[1].x * o[1].x;
        s4.y = o[0].y + o[1].y;  q4.y = o[0].y * o[0].y + o[1].y * o[1].y;
        s4.z = o[0].z + o[1].z;  q4.z = o[0].z * o[0].z + o[1].z * o[1].z;
        s4.w = o[0].w + o[1].w;  q4.w = o[0].w * o[0].w + o[1].w * o[1].w;
        *(float4*)(S + brow * 64 + j4) = s4;
        *(float4*)(Q + brow * 64 + j4) = q4;
        __syncthreads();
        if (tid < 64) {
            float s = 0.f, q = 0.f;
#pragma unroll
            for (int t = 0; t < 16; ++t) { s += S[t * 64 + tid]; q += Q[t * 64 + tid]; }
            atomicAdd(&stats[tid], s);
            atomicAdd(&stats[64 + tid], q);
        }
    }
}

__global__ void k_bnfin(const float* __restrict__ stats, const float* __restrict__ g,
                        const float* __restrict__ be, float* st) {
    int c = threadIdx.x;  // 64
    const float inv = 1.0f / (float)(NB * NN);
    float mu = stats[c] * inv;
    float var = stats[64 + c] * inv - mu * mu;
    float sc = g[c] / sqrtf(var + 1e-5f);
    st[c] = sc;
    st[64 + c] = fmaf(-mu, sc, be[c]);
}

// ---------------- global_sort_pool: top-30 stable argmax ----------------
__global__ void k_toppool(const float* __restrict__ h3, int* order) {
    __shared__ float v[NN];
    __shared__ float bestv[256];
    __shared__ int besti[256];
    int b = blockIdx.x, tid = threadIdx.x;
    for (int i = tid; i < NN; i += 256)
        v[i] = fmaxf(h3[((size_t)i * NB + b) * 64 + 63], 0.f);  // relu'd last channel
    __syncthreads();
    for (int k = 0; k < KPOOL; ++k) {
        float bv = -1.f; int bi = NN;
        for (int i = tid; i < NN; i += 256) {
            float x = v[i];
            if (x > bv || (x == bv && i < bi)) { bv = x; bi = i; }
        }
        bestv[tid] = bv; besti[tid] = bi;
        __syncthreads();
        for (int off = 128; off > 0; off >>= 1) {
            if (tid < off) {
                float ov = bestv[tid + off]; int oi = besti[tid + off];
                if (ov > bestv[tid] || (ov == bestv[tid] && oi < besti[tid])) {
                    bestv[tid] = ov; besti[tid] = oi;
                }
            }
            __syncthreads();
        }
        if (tid == 0) { order[b * KPOOL + k] = besti[0]; v[besti[0]] = -1.f; }
        __syncthreads();
    }
}

// ---------------- gather selected nodes into flat (B, 6241) ----------------
__global__ void k_gather(const float* __restrict__ xt, const float* __restrict__ h1,
                         const float* __restrict__ h2, const float* __restrict__ h3,
                         const float* __restrict__ st, const float* __restrict__ age,
                         const int* __restrict__ order, float* __restrict__ flat) {
    int bk = blockIdx.x;
    int b = bk / KPOOL, k = bk % KPOOL;
    int n = order[bk];
    int f = threadIdx.x;
    float val = 0.f;
    if (f < DIN) {
        val = xt[((size_t)n * NB + b) * DIN + f];
    } else if (f < DIN + CH) {
        int c = f - DIN;
        val = fmaxf(fmaf(h1[((size_t)n * NB + b) * CH + c], st[c], st[64 + c]), 0.f);
    } else if (f < DIN + 2 * CH) {
        int c = f - DIN - CH;
        val = fmaxf(fmaf(h2[((size_t)n * NB + b) * CH + c], st[128 + c], st[192 + c]), 0.f);
    } else if (f < FTOT) {
        int c = f - DIN - 2 * CH;
        val = fmaxf(h3[((size_t)n * NB + b) * CH + c], 0.f);
    }
    if (f < FTOT) flat[(size_t)b * FLATW + k * FTOT + f] = val;
    if (bk == 0 && f >= FTOT && f < FTOT + NB)
        flat[(size_t)(f - FTOT) * FLATW + (FLATW - 1)] = age[f - FTOT];
}

// ---------------- MLP head layer 1: hm += flat @ mW0 (k-split, atomics) ----------------
__global__ void k_head1(const float* __restrict__ flat, const float* __restrict__ mW0,
                        float* hm) {
    int tid = threadIdx.x;
    int j4 = (tid & 31) * 4;       // 32 groups * 4 = 128 cols
    int b0 = (tid >> 5) * 4;       // 8 groups * 4 = 32 rows
    int kbase = blockIdx.x * 64;
    float acc[4][4];
#pragma unroll
    for (int i = 0; i < 4; i++)
#pragma unroll
        for (int jj = 0; jj < 4; jj++) acc[i][jj] = 0.f;
    int kend = FLATW - kbase; if (kend > 64) kend = 64;
    for (int kk = 0; kk < kend; ++kk) {
        int k = kbase + kk;
        float4 w = *(const float4*)(mW0 + (size_t)k * NH + j4);
#pragma unroll
        for (int i = 0; i < 4; i++) {
            float fv = flat[(size_t)(b0 + i) * FLATW + k];
            acc[i][0] = fmaf(fv, w.x, acc[i][0]);
            acc[i][1] = fmaf(fv, w.y, acc[i][1]);
            acc[i][2] = fmaf(fv, w.z, acc[i][2]);
            acc[i][3] = fmaf(fv, w.w, acc[i][3]);
        }
    }
#pragma unroll
    for (int i = 0; i < 4; i++)
#pragma unroll
        for (int jj = 0; jj < 4; jj++)
            atomicAdd(&hm[(size_t)(b0 + i) * NH + j4 + jj], acc[i][jj]);
}

// ---------------- head layer 2 + log_softmax ----------------
__global__ void k_head2(const float* __restrict__ hm, const float* __restrict__ mb0,
                        const float* __restrict__ mW1, const float* __restrict__ mb1,
                        float* __restrict__ out) {
    __shared__ float vals[64];
    int tid = threadIdx.x;  // 64 = 32 b * 2 o
    int b = tid >> 1, o = tid & 1;
    float acc = mb1[o];
    for (int j = 0; j < NH; ++j) {
        float hv = fmaxf(hm[b * NH + j] + mb0[j], 0.f);
        acc = fmaf(hv, mW1[j * 2 + o], acc);
    }
    vals[tid] = acc;
    __syncthreads();
    float v0 = vals[b * 2], v1 = vals[b * 2 + 1];
    float m = fmaxf(v0, v1);
    float lse = m + logf(expf(v0 - m) + expf(v1 - m));
    out[tid] = acc - lse;
}

extern "C" void kernel_launch(void* const* d_in, const int* in_sizes, int n_in,
                              void* d_out, int out_size, void* d_ws, size_t ws_size,
                              hipStream_t stream) {
    const float* x    = (const float*)d_in[0];
    const float* age  = (const float*)d_in[1];
    const float* attr = (const float*)d_in[2];
    const float* W0   = (const float*)d_in[3];
    const float* b0   = (const float*)d_in[4];
    const float* W1   = (const float*)d_in[5];
    const float* b1   = (const float*)d_in[6];
    const float* W2   = (const float*)d_in[7];
    const float* b2   = (const float*)d_in[8];
    const float* g0   = (const float*)d_in[9];
    const float* be0  = (const float*)d_in[10];
    const float* g1   = (const float*)d_in[11];
    const float* be1  = (const float*)d_in[12];
    const float* mW0  = (const float*)d_in[13];
    const float* mb0  = (const float*)d_in[14];
    const float* mW1  = (const float*)d_in[15];
    const float* mb1  = (const float*)d_in[16];
    const int* erow   = (const int*)d_in[17];
    const int* ecol   = (const int*)d_in[18];
    float* out = (float*)d_out;

    // workspace layout (floats); all float4-aligned
    float* ws     = (float*)d_ws;
    float* deg    = ws;                                  // 5008
    float* dinv   = deg + 5008;                          // 5008
    int*   counts = (int*)(dinv + 5008);                 // 5008
    int*   rowptr = counts + 5008;                       // 5008
    int*   cursor = rowptr + 5008;                       // 5008
    int*   csr_col= cursor + 5008;                       // 80000
    float* csr_nv = (float*)(csr_col + 80000);           // 80000
    float* stats  = csr_nv + 80000;                      // 256
    float* st     = stats + 256;                         // 256 (s0,t0,s1,t1)
    int*   order  = (int*)(st + 256);                    // 960
    float* flat   = (float*)(order + 960);               // 32*6241
    float* hm     = flat + (size_t)NB * FLATW;           // 4096
    float* xt     = hm + 4096;                           // 32*5000*16  (node-major x)
    float* h1     = xt + (size_t)NB * NN * DIN;          // 32*5000*64 each, node-major
    float* h2     = h1 + (size_t)NB * NN * CH;
    float* h3     = h2 + (size_t)NB * NN * CH;

    // graph build
    k_init<<<20, 256, 0, stream>>>(deg, counts, stats, hm);
    k_edges<<<(NE + 255) / 256, 256, 0, stream>>>(attr, erow, deg, counts);
    k_dinv<<<(NN + 255) / 256, 256, 0, stream>>>(deg, dinv);
    k_scan<<<1, 1024, 0, stream>>>(counts, rowptr, cursor);
    k_scatter<<<(NE + 255) / 256, 256, 0, stream>>>(erow, ecol, attr, dinv, cursor, csr_col, csr_nv);
    k_transpose<<<(NB * NN + 255) / 256, 256, 0, stream>>>(x, xt);

    // fused layers (spmm + gemm + bn-stats)
    k_layer<16, 0, 1><<<NN, 256, 0, stream>>>(xt, nullptr, W0, b0, rowptr, csr_col, csr_nv, dinv, h1, stats);
    k_bnfin<<<1, 64, 0, stream>>>(stats, g0, be0, st);
    k_layer<64, 1, 1><<<NN, 256, 0, stream>>>(h1, st, W1, b1, rowptr, csr_col, csr_nv, dinv, h2, stats + 128);
    k_bnfin<<<1, 64, 0, stream>>>(stats + 128, g1, be1, st + 128);
    k_layer<64, 1, 0><<<NN, 256, 0, stream>>>(h2, st + 128, W2, b2, rowptr, csr_col, csr_nv, dinv, h3, nullptr);

    // sort-pool + gather + head
    k_toppool<<<NB, 256, 0, stream>>>(h3, order);
    k_gather<<<NB * KPOOL, 256, 0, stream>>>(xt, h1, h2, h3, st, age, order, flat);
    k_head1<<<(FLATW + 63) / 64, 256, 0, stream>>>(flat, mW0, hm);
    k_head2<<<1, 64, 0, stream>>>(hm, mb0, mW1, mb1, out);
}